// Round 4
// baseline (91.079 us; speedup 1.0000x reference)
//
#include <hip/hip_runtime.h>
#include <stdint.h>
#include <stddef.h>

typedef int   v4i __attribute__((ext_vector_type(4)));
typedef float v4f __attribute__((ext_vector_type(4)));

#define M_DIM 32768
#define N_DIM 1024
#define K_DIM 1024
#define BM 256
#define BN 256
#define BK 128            // int8 elems per K-tile (128 B rows)
#define NT (K_DIM / BK)   // 8 K-tiles

typedef const __attribute__((address_space(1))) void gvoid_t;
typedef __attribute__((address_space(3))) void lvoid_t;

__device__ __forceinline__ void gload16(const void* g, void* l) {
    // global->LDS DMA, 16B/lane; LDS dest = wave-uniform base + lane*16
    __builtin_amdgcn_global_load_lds((gvoid_t*)g, (lvoid_t*)l, 16, 0, 0);
}

#define VMCNT(n)  asm volatile("s_waitcnt vmcnt(" #n ")" ::: "memory")
// HARDENED barrier: volatile asm with memory clobber so NO load/store can be
// hoisted/sunk across it at IR level (raw s_barrier builtin is IntrNoMem ->
// LDS reads could cross it: the R3 race). sched_barrier(0) pins the MIR
// scheduler too.
#define BARRIER() do { asm volatile("s_barrier" ::: "memory"); \
                       __builtin_amdgcn_sched_barrier(0); } while (0)

// ---------------- pass 0: repack weight int32 -> packed int8 ----------------
__global__ __launch_bounds__(256)
void repack_w_kernel(const int* __restrict__ wi, int* __restrict__ wq, int n4)
{
    int i = blockIdx.x * blockDim.x + threadIdx.x;
    if (i < n4) {
        v4i v = ((const v4i*)wi)[i];
        wq[i] = (v[0] & 255) | ((v[1] & 255) << 8) |
                ((v[2] & 255) << 16) | ((v[3] & 255) << 24);
    }
}

// ---------------- pass 1: quantize fp32 -> int8 (row-major [M][K]) ----------
__global__ __launch_bounds__(256, 2)
void quant_kernel(const float* __restrict__ x, int* __restrict__ q,
                  const float* __restrict__ iscale_p, int n4)
{
    const float inv = 1.0f / *iscale_p;
    int idx = blockIdx.x * blockDim.x + threadIdx.x;
    int stride = gridDim.x * blockDim.x;
    const v4f* xp = (const v4f*)x;
    for (int i = idx; i < n4; i += stride) {
        v4f v = xp[i];
        int r = 0;
        #pragma unroll
        for (int j = 0; j < 4; ++j) {
            float t = rintf(v[j] * inv);
            t = fminf(127.f, fmaxf(-128.f, t));
            r |= ((int)t & 255) << (8 * j);
        }
        q[i] = r;
    }
}

// ---------------- staging helpers (both-sides swizzle: col ^= (row&7)<<4) ---
// A half q: rows {r : (r&127)>>6 == q} of the [256][BK] tile; 2 loads/thread.
__device__ __forceinline__ void stageA(const signed char* __restrict__ gA,
                                       signed char* ldsA, int q, int wv, int ln)
{
    #pragma unroll
    for (int l = 0; l < 2; ++l) {
        const int r0  = l * 128 + q * 64 + wv * 8;            // wave-uniform
        const int row = r0 + (ln >> 3);
        const int col = ((ln & 7) * 16) ^ ((ln >> 3) << 4);   // (row&7)==ln>>3
        gload16(gA + (size_t)row * K_DIM + col, ldsA + r0 * BK);
    }
}
// B half q: rows {r : (r&63)>>5 == q}; 2 loads/thread.
__device__ __forceinline__ void stageB(const signed char* __restrict__ gB,
                                       signed char* ldsB, int q, int wv, int ln)
{
    #pragma unroll
    for (int l = 0; l < 2; ++l) {
        const int r0  = (2 * l + (wv >> 2)) * 64 + q * 32 + (wv & 3) * 8;
        const int row = r0 + (ln >> 3);
        const int col = ((ln & 7) * 16) ^ ((ln >> 3) << 4);
        gload16(gB + (size_t)row * K_DIM + col, ldsB + r0 * BK);
    }
}

__device__ __forceinline__ v4i ldsRead(const signed char* lds, int row, int colb)
{
    return *(const v4i*)(lds + row * BK + (colb ^ ((row & 7) << 4)));
}

// ---------------- pass 2: int8 GEMM, 256x256 tile, 8-phase schedule ---------
__global__ __launch_bounds__(512, 2)
void qgemm_kernel(const signed char* __restrict__ Aq,
                  const signed char* __restrict__ W,
                  const float* __restrict__ wscale,
                  const float* __restrict__ iscale_p,
                  const float* __restrict__ bias,
                  float* __restrict__ out)
{
    __shared__ signed char lA[2][BM * BK];   // 2 x 32 KiB
    __shared__ signed char lB[2][BN * BK];   // 2 x 32 KiB  (128 KiB total)

    // XCD-bijective swizzle: 512 blocks, 64 per XCD chunk.
    const int bid = blockIdx.x;
    const int wg  = (bid & 7) * 64 + (bid >> 3);
    const int m_blk = wg >> 2;               // 128 row-blocks
    const int n_blk = wg & 3;                // 4 col-blocks
    const int mrow0 = m_blk * BM;
    const int ncol0 = n_blk * BN;

    const int tid = threadIdx.x;
    const int wv  = tid >> 6;                // 0..7
    const int ln  = tid & 63;
    const int wm  = wv >> 2;                 // 2 wave-rows (128 rows each)
    const int wn  = wv & 3;                  // 4 wave-cols (64 cols each)
    const int lr  = ln & 15;                 // fragment row / C col
    const int kc  = (ln >> 4) * 16;          // fragment K-chunk byte offset

    const signed char* gA = Aq + (size_t)mrow0 * K_DIM;
    const signed char* gB = W  + (size_t)ncol0 * K_DIM;

    v4i acc[8][4] = {};
    v4i aF[4][2];        // resident A half: 4 m-frags x 2 ksteps
    v4i bF[2][2][2];     // [half][n'][ks] both B halves resident

    // Prologue: tile 0 halves in order A0, B0, B1, A1 (8 loads/thread).
    stageA(gA, lA[0], 0, wv, ln);
    stageB(gB, lB[0], 0, wv, ln);
    stageB(gB, lB[0], 1, wv, ln);
    stageA(gA, lA[0], 1, wv, ln);

    #pragma unroll
    for (int t = 0; t < NT; ++t) {
        const signed char* cA = lA[t & 1];
        const signed char* cB = lB[t & 1];
        signed char* nA = lA[(t + 1) & 1];
        signed char* nB = lB[(t + 1) & 1];
        const size_t ktn = (size_t)(t + 1) * BK;
        const bool st = (t + 1 < NT);

        // ---- phase 0: quadrant (qm=0,qn=0); needs A0,B0 of tile t ----------
        VMCNT(4);                       // outstanding: B1^t, A1^t (4 loads)
        BARRIER();
        #pragma unroll
        for (int m = 0; m < 4; ++m)
            #pragma unroll
            for (int ks = 0; ks < 2; ++ks)
                aF[m][ks] = ldsRead(cA, wm * 128 + m * 16 + lr, ks * 64 + kc);
        #pragma unroll
        for (int n = 0; n < 2; ++n)
            #pragma unroll
            for (int ks = 0; ks < 2; ++ks)
                bF[0][n][ks] = ldsRead(cB, wn * 64 + n * 16 + lr, ks * 64 + kc);
        if (st) stageA(gA + ktn, nA, 0, wv, ln);
        BARRIER();
        __builtin_amdgcn_s_setprio(1);
        #pragma unroll
        for (int m = 0; m < 4; ++m)
            #pragma unroll
            for (int n = 0; n < 2; ++n)
                #pragma unroll
                for (int ks = 0; ks < 2; ++ks)
                    acc[m][n] = __builtin_amdgcn_mfma_i32_16x16x64_i8(
                                    aF[m][ks], bF[0][n][ks], acc[m][n], 0, 0, 0);
        __builtin_amdgcn_s_setprio(0);

        // ---- phase 1: quadrant (0,1); needs B1 of tile t -------------------
        if (st) { VMCNT(4); } else { VMCNT(2); }   // outstanding: A1^t [, A0^{t+1}]
        BARRIER();
        #pragma unroll
        for (int n = 0; n < 2; ++n)
            #pragma unroll
            for (int ks = 0; ks < 2; ++ks)
                bF[1][n][ks] = ldsRead(cB, wn * 64 + 32 + n * 16 + lr, ks * 64 + kc);
        if (st) stageB(gB + ktn, nB, 0, wv, ln);
        BARRIER();
        __builtin_amdgcn_s_setprio(1);
        #pragma unroll
        for (int m = 0; m < 4; ++m)
            #pragma unroll
            for (int n = 0; n < 2; ++n)
                #pragma unroll
                for (int ks = 0; ks < 2; ++ks)
                    acc[m][2 + n] = __builtin_amdgcn_mfma_i32_16x16x64_i8(
                                    aF[m][ks], bF[1][n][ks], acc[m][2 + n], 0, 0, 0);
        __builtin_amdgcn_s_setprio(0);

        // ---- phase 2: quadrant (1,1); needs A1 of tile t -------------------
        if (st) { VMCNT(4); } else { VMCNT(0); }   // tail drain
        BARRIER();
        #pragma unroll
        for (int m = 0; m < 4; ++m)
            #pragma unroll
            for (int ks = 0; ks < 2; ++ks)
                aF[m][ks] = ldsRead(cA, wm * 128 + 64 + m * 16 + lr, ks * 64 + kc);
        if (st) stageB(gB + ktn, nB, 1, wv, ln);
        BARRIER();
        __builtin_amdgcn_s_setprio(1);
        #pragma unroll
        for (int m = 0; m < 4; ++m)
            #pragma unroll
            for (int n = 0; n < 2; ++n)
                #pragma unroll
                for (int ks = 0; ks < 2; ++ks)
                    acc[4 + m][2 + n] = __builtin_amdgcn_mfma_i32_16x16x64_i8(
                                    aF[m][ks], bF[1][n][ks], acc[4 + m][2 + n], 0, 0, 0);
        __builtin_amdgcn_s_setprio(0);

        // ---- phase 3: quadrant (1,0); reuses aF(A1), bF[0](B0) -------------
        BARRIER();
        if (st) stageA(gA + ktn, nA, 1, wv, ln);
        BARRIER();
        __builtin_amdgcn_s_setprio(1);
        #pragma unroll
        for (int m = 0; m < 4; ++m)
            #pragma unroll
            for (int n = 0; n < 2; ++n)
                #pragma unroll
                for (int ks = 0; ks < 2; ++ks)
                    acc[4 + m][n] = __builtin_amdgcn_mfma_i32_16x16x64_i8(
                                    aF[m][ks], bF[0][n][ks], acc[4 + m][n], 0, 0, 0);
        __builtin_amdgcn_s_setprio(0);
    }

    // Epilogue: dequant + bias. C/D: col = ln&15, row = (ln>>4)*4 + r.
    const float is = *iscale_p;
    #pragma unroll
    for (int n = 0; n < 4; ++n) {
        const int col = ncol0 + wn * 64 + n * 16 + lr;
        const float sc = wscale[col] * is;
        const float bv = bias[col];
        #pragma unroll
        for (int m = 0; m < 8; ++m) {
            const int row = mrow0 + wm * 128 + m * 16 + ((ln >> 4) << 2);
            #pragma unroll
            for (int r = 0; r < 4; ++r)
                out[(size_t)(row + r) * N_DIM + col] = (float)acc[m][n][r] * sc + bv;
        }
    }
}

extern "C" void kernel_launch(void* const* d_in, const int* in_sizes, int n_in,
                              void* d_out, int out_size, void* d_ws, size_t ws_size,
                              hipStream_t stream)
{
    const float* x       = (const float*)d_in[0];
    const int*   w32     = (const int*)d_in[1];   // int8 weight stored as int32 [N][K]
    const float* wscale  = (const float*)d_in[2];
    const float* iscale  = (const float*)d_in[3];
    const float* bias    = (const float*)d_in[4];
    float* out           = (float*)d_out;

    signed char* aq = (signed char*)d_ws;                          // 32 MiB
    signed char* wq = (signed char*)d_ws + (size_t)M_DIM * K_DIM;  // +1 MiB

    const int wn4 = (N_DIM * K_DIM) / 4;
    repack_w_kernel<<<(wn4 + 255) / 256, 256, 0, stream>>>(w32, (int*)wq, wn4);

    quant_kernel<<<8192, 256, 0, stream>>>(x, (int*)aq, iscale, (M_DIM * K_DIM) / 4);

    const int grid = (M_DIM / BM) * (N_DIM / BN);   // 512 blocks
    qgemm_kernel<<<grid, 512, 0, stream>>>(aq, wq, wscale, iscale, bias, out);
}